// Round 4
// baseline (2874.994 us; speedup 1.0000x reference)
//
#include <hip/hip_runtime.h>
#include <hip/hip_cooperative_groups.h>
#include <math.h>

namespace cg = cooperative_groups;

#define N_NODES 40000
#define N_EDGES 512000
#define SDIM 128
#define EDIM 128
#define HID 64
#define DEPTH 4
#define MSG_IN 386   // 2*SDIM + EDIM + 2
#define SCAL_IN 192  // SDIM + HID
#define CUTOFF 5.0f
#define EPS_D 1e-6f

#define TILE_M 16
#define CW 16                    // waves per block
#define CTHREADS 1024
#define CBLOCKS 256
#define GWAVES (CBLOCKS * CW)    // 4096
#define NTILES (N_EDGES / TILE_M)  // 32000

typedef __attribute__((ext_vector_type(8))) short short8;
typedef __attribute__((ext_vector_type(4))) float f32x4;

struct Params {
  const float *s_in, *v_in, *e_in;
  const int *srcs, *dsts;
  const float *ead;
  const float *We1, *be1, *We2, *be2, *Weo, *beo, *Wv, *bv, *Ws1, *bs1, *Ws2, *bs2;
  float *out_s, *out_v, *out_e;
  float *deginv, *v_acc, *agg, *Sa, *Sb;
};

__device__ __forceinline__ float silu_f(float x) { return x / (1.0f + __expf(-x)); }

__device__ __forceinline__ unsigned short f2b(float x) {
  union { float f; unsigned int u; } v; v.f = x;
  unsigned int r = v.u + 0x7FFFu + ((v.u >> 16) & 1u);
  return (unsigned short)(r >> 16);
}

__device__ __forceinline__ short8 pack8(f32x4 lo, f32x4 hi) {
  union { unsigned short u[8]; short8 s; } pk;
  pk.u[0] = f2b(lo[0]); pk.u[1] = f2b(lo[1]); pk.u[2] = f2b(lo[2]); pk.u[3] = f2b(lo[3]);
  pk.u[4] = f2b(hi[0]); pk.u[5] = f2b(hi[1]); pk.u[6] = f2b(hi[2]); pk.u[7] = f2b(hi[3]);
  return pk.s;
}

// One persistent cooperative kernel: init + DEPTH x (node_pre | edges | node_upd)
// Fragment layouts (verified in round 3, absmax 0.031):
//   A[m][k]: m=lane&15, k=(lane>>4)*8+i per 32-wide kc block
//   B[k][n]: n=lane&15, k=(lane>>4)*8+i
//   D[m][n]: n=lane&15, m=(lane>>4)*4+reg
__global__ __launch_bounds__(CTHREADS, 4) void k_all(Params p) {
  cg::grid_group grid = cg::this_grid();

  __shared__ __align__(16) unsigned short W1t[64 * 136];    // [n][k] K=128+8
  __shared__ __align__(16) unsigned short We2t[64 * 72];    // [n][k] K=64+8
  __shared__ __align__(16) unsigned short WeoT[128 * 72];   // [n][k] K=64+8
  __shared__ __align__(16) unsigned short hmS[CW][16 * 72]; // per-wave h/m transpose buf
  __shared__ __align__(16) float sbufS[CW][128];            // per-wave scalars / s-row

  const int tid = threadIdx.x;
  const int lane = tid & 63;
  const int w = tid >> 6;
  const int gw = blockIdx.x * CW + w;
  const int c = lane & 15;   // A-row / B-col / D-col
  const int g = lane >> 4;   // k-group / D-row-group

  float* sb = sbufS[w];
  int* sbi = (int*)sb;
  unsigned short* hw = hmS[w];
  float* hf = (float*)hmS[w];   // node-phase reuse (64 floats fit in 2304B)

  // ---------------- init: deg ----------------
  {
    const int gt = blockIdx.x * CTHREADS + tid;
    for (int i = gt; i < (1 + 3 + 64) * N_NODES; i += CBLOCKS * CTHREADS)
      p.deginv[i] = 0.0f;   // deginv, v_acc, agg contiguous
    grid.sync();
    for (int i = gt; i < N_EDGES; i += CBLOCKS * CTHREADS)
      atomicAdd(&p.deginv[p.dsts[i]], 1.0f);
    grid.sync();
    for (int i = gt; i < N_NODES; i += CBLOCKS * CTHREADS)
      p.deginv[i] = 1.0f / fmaxf(p.deginv[i], 1.0f);
    grid.sync();
  }

  for (int d = 0; d < DEPTH; ++d) {
    const float* scur = d ? p.out_s : p.s_in;
    const float* vcur = d ? p.out_v : p.v_in;
    const float* ecur = d ? p.out_e : p.e_in;
    const float* W1i = p.We1 + (size_t)d * MSG_IN * HID;
    const float* W1e = W1i + 256 * HID;
    const float* w1d = W1i + 384 * HID;
    const float* w1a = W1i + 385 * HID;
    const float* We2d = p.We2 + (size_t)d * HID * HID;
    const float* Weod = p.Weo + (size_t)d * HID * EDIM;
    const float* Ws1d = p.Ws1 + (size_t)d * SCAL_IN * HID;
    const float* Ws2d = p.Ws2 + (size_t)d * HID * SDIM;

    // ---- stage edge weights to LDS (phase A below doesn't touch these regions) ----
    for (int idx = tid; idx < 128 * 64; idx += CTHREADS) {
      const int k = idx >> 6, n = idx & 63;
      W1t[n * 136 + k] = f2b(W1e[idx]);
    }
    for (int idx = tid; idx < 64 * 64; idx += CTHREADS) {
      const int k = idx >> 6, n = idx & 63;
      We2t[n * 72 + k] = f2b(We2d[idx]);
    }
    for (int idx = tid; idx < 64 * 128; idx += CTHREADS) {
      const int k = idx >> 7, n = idx & 127;
      WeoT[n * 72 + k] = f2b(Weod[idx]);
    }

    // ---- phase A: Sa = s@We1[0:128]+be1, Sb = s@We1[128:256] (wave per node) ----
    {
      const float* be1d = p.be1 + d * HID;
      for (int node = gw; node < N_NODES; node += GWAVES) {
        const float2 s2 = reinterpret_cast<const float2*>(scur + (size_t)node * SDIM)[lane];
        reinterpret_cast<float2*>(sb)[lane] = s2;
        float a = be1d[lane], b = 0.0f;
#pragma unroll 8
        for (int k = 0; k < SDIM; ++k) {
          const float sk = sb[k];
          a = fmaf(sk, W1i[k * HID + lane], a);
          b = fmaf(sk, W1i[(SDIM + k) * HID + lane], b);
        }
        p.Sa[(size_t)node * HID + lane] = a;
        p.Sb[(size_t)node * HID + lane] = b;
      }
    }
    grid.sync();   // Sa/Sb + staged weights visible

    // ---- phase B: edges (wave per 16-edge tile) ----
    {
      float w1d_l[4], w1a_l[4], be2_l[4], Wv_l[4], beo_l[8];
      const float* be2d = p.be2 + d * HID;
      const float* beod = p.beo + d * EDIM;
      const float* Wvd = p.Wv + d * HID;
#pragma unroll
      for (int nt = 0; nt < 4; ++nt) {
        w1d_l[nt] = w1d[nt * 16 + c];
        w1a_l[nt] = w1a[nt * 16 + c];
        be2_l[nt] = be2d[nt * 16 + c];
        Wv_l[nt] = Wvd[nt * 16 + c];
      }
#pragma unroll
      for (int nt = 0; nt < 8; ++nt) beo_l[nt] = beod[nt * 16 + c];
      const float bv0 = p.bv[d];

      for (int t = gw; t < NTILES; t += GWAVES) {
        const int e0 = t * TILE_M;
        if (lane < 16) {
          const int eid = e0 + lane;
          const int s_ = p.srcs[eid], d_ = p.dsts[eid];
          const float dx = vcur[s_ * 3 + 0] - vcur[d_ * 3 + 0];
          const float dy = vcur[s_ * 3 + 1] - vcur[d_ * 3 + 1];
          const float dz = vcur[s_ * 3 + 2] - vcur[d_ * 3 + 2];
          const float dist = sqrtf(dx * dx + dy * dy + dz * dz + EPS_D);
          const float cwv = (dist < CUTOFF)
                                ? 0.5f * (__cosf((float)M_PI / CUTOFF * dist) + 1.0f)
                                : 0.0f;
          sb[lane] = dist; sb[16 + lane] = cwv; sb[32 + lane] = p.ead[eid];
          sb[48 + lane] = dx; sb[64 + lane] = dy; sb[80 + lane] = dz;
          sbi[96 + lane] = s_; sbi[112 + lane] = d_;
        }
        int src_r[4], dst_r[4];
        float dist_r[4], cw_r[4], ea_r[4];
#pragma unroll
        for (int r = 0; r < 4; ++r) {
          const int row = g * 4 + r;
          dist_r[r] = sb[row]; cw_r[r] = sb[16 + row]; ea_r[r] = sb[32 + row];
          src_r[r] = sbi[96 + row]; dst_r[r] = sbi[112 + row];
        }

        // G1 init: Sa[src]+Sb[dst]+dist*w1d+ea*w1a
        f32x4 acc[4];
#pragma unroll
        for (int nt = 0; nt < 4; ++nt)
#pragma unroll
          for (int r = 0; r < 4; ++r)
            acc[nt][r] = p.Sa[(size_t)src_r[r] * HID + nt * 16 + c]
                       + p.Sb[(size_t)dst_r[r] * HID + nt * 16 + c]
                       + dist_r[r] * w1d_l[nt] + ea_r[r] * w1a_l[nt];

        // G1: A-frags loaded direct from global (lane c owns row e0+c)
        const float* erow = ecur + (size_t)(e0 + c) * EDIM;
#pragma unroll
        for (int kc = 0; kc < 4; ++kc) {
          const f32x4 lo = *(const f32x4*)&erow[kc * 32 + g * 8];
          const f32x4 hi = *(const f32x4*)&erow[kc * 32 + g * 8 + 4];
          const short8 af = pack8(lo, hi);
#pragma unroll
          for (int nt = 0; nt < 4; ++nt) {
            const short8 bf = *(const short8*)&W1t[(nt * 16 + c) * 136 + kc * 32 + g * 8];
            acc[nt] = __builtin_amdgcn_mfma_f32_16x16x32_bf16(af, bf, acc[nt], 0, 0, 0);
          }
        }
        // h1 -> per-wave LDS (bf16, A-layout)
#pragma unroll
        for (int nt = 0; nt < 4; ++nt)
#pragma unroll
          for (int r = 0; r < 4; ++r)
            hw[(g * 4 + r) * 72 + nt * 16 + c] = f2b(silu_f(acc[nt][r]));

        // G2
        f32x4 acc2[4];
#pragma unroll
        for (int nt = 0; nt < 4; ++nt)
          acc2[nt] = f32x4{be2_l[nt], be2_l[nt], be2_l[nt], be2_l[nt]};
#pragma unroll
        for (int kc = 0; kc < 2; ++kc) {
          const short8 am = *(const short8*)&hw[c * 72 + kc * 32 + g * 8];
#pragma unroll
          for (int nt = 0; nt < 4; ++nt) {
            const short8 bf = *(const short8*)&We2t[(nt * 16 + c) * 72 + kc * 32 + g * 8];
            acc2[nt] = __builtin_amdgcn_mfma_f32_16x16x32_bf16(am, bf, acc2[nt], 0, 0, 0);
          }
        }
        float mval[4][4];
#pragma unroll
        for (int nt = 0; nt < 4; ++nt)
#pragma unroll
          for (int r = 0; r < 4; ++r)
            mval[nt][r] = silu_f(acc2[nt][r]) * cw_r[r];

        // agg atomics + wv reduce + v_acc atomics
        float tr[4] = {0.f, 0.f, 0.f, 0.f};
#pragma unroll
        for (int nt = 0; nt < 4; ++nt)
#pragma unroll
          for (int r = 0; r < 4; ++r) {
            tr[r] = fmaf(mval[nt][r], Wv_l[nt], tr[r]);
            atomicAdd(&p.agg[(size_t)dst_r[r] * HID + nt * 16 + c], mval[nt][r]);
          }
#pragma unroll
        for (int r = 0; r < 4; ++r) {
          float s = tr[r];
          s += __shfl_xor(s, 1); s += __shfl_xor(s, 2);
          s += __shfl_xor(s, 4); s += __shfl_xor(s, 8);
          const float wvv = s + bv0;
          if (c < 3) {
            const int row = g * 4 + r;
            atomicAdd(&p.v_acc[(size_t)dst_r[r] * 3 + c], sb[48 + 16 * c + row] * wvv);
          }
        }

        // m -> per-wave LDS (bf16, A-layout)
#pragma unroll
        for (int nt = 0; nt < 4; ++nt)
#pragma unroll
          for (int r = 0; r < 4; ++r)
            hw[(g * 4 + r) * 72 + nt * 16 + c] = f2b(mval[nt][r]);

        // GEMMo
        f32x4 oacc[8];
#pragma unroll
        for (int nt = 0; nt < 8; ++nt) oacc[nt] = f32x4{0.f, 0.f, 0.f, 0.f};
#pragma unroll
        for (int kc = 0; kc < 2; ++kc) {
          const short8 am = *(const short8*)&hw[c * 72 + kc * 32 + g * 8];
#pragma unroll
          for (int nt = 0; nt < 8; ++nt) {
            const short8 bf = *(const short8*)&WeoT[(nt * 16 + c) * 72 + kc * 32 + g * 8];
            oacc[nt] = __builtin_amdgcn_mfma_f32_16x16x32_bf16(am, bf, oacc[nt], 0, 0, 0);
          }
        }
        // residual + bias + store (direct, coalesced per 16-lane group)
#pragma unroll
        for (int nt = 0; nt < 8; ++nt)
#pragma unroll
          for (int r = 0; r < 4; ++r) {
            const size_t gi = (size_t)(e0 + g * 4 + r) * EDIM + nt * 16 + c;
            p.out_e[gi] = oacc[nt][r] + beo_l[nt] + ecur[gi];
          }
      }
    }
    grid.sync();

    // ---- phase C: node update (wave per node); re-zero v_acc/agg ----
    {
      const float* bs1d = p.bs1 + d * HID;
      const float* bs2d = p.bs2 + d * SDIM;
      for (int node = gw; node < N_NODES; node += GWAVES) {
        const float di = p.deginv[node];
        if (lane < 3) {
          p.out_v[(size_t)node * 3 + lane] = vcur[(size_t)node * 3 + lane]
                                           + p.v_acc[(size_t)node * 3 + lane] * di;
          p.v_acc[(size_t)node * 3 + lane] = 0.0f;
        }
        const float2 s2 = reinterpret_cast<const float2*>(scur + (size_t)node * SDIM)[lane];
        reinterpret_cast<float2*>(sb)[lane] = s2;
        const float aj = p.agg[(size_t)node * HID + lane] * di;
        p.agg[(size_t)node * HID + lane] = 0.0f;
        hf[lane] = aj;
        float acc = bs1d[lane];
#pragma unroll 8
        for (int k = 0; k < SDIM; ++k) acc = fmaf(sb[k], Ws1d[k * HID + lane], acc);
#pragma unroll 8
        for (int k = 0; k < HID; ++k) acc = fmaf(hf[k], Ws1d[(SDIM + k) * HID + lane], acc);
        const float h = silu_f(acc);
        hf[lane] = h;
        float o1 = bs2d[lane] + sb[lane];
        float o2 = bs2d[64 + lane] + sb[64 + lane];
#pragma unroll 8
        for (int k = 0; k < HID; ++k) {
          const float hk = hf[k];
          o1 = fmaf(hk, Ws2d[k * SDIM + lane], o1);
          o2 = fmaf(hk, Ws2d[k * SDIM + 64 + lane], o2);
        }
        p.out_s[(size_t)node * SDIM + lane] = o1;
        p.out_s[(size_t)node * SDIM + 64 + lane] = o2;
      }
    }
    grid.sync();
  }
}

extern "C" void kernel_launch(void* const* d_in, const int* in_sizes, int n_in,
                              void* d_out, int out_size, void* d_ws, size_t ws_size,
                              hipStream_t stream) {
  Params pr;
  pr.s_in = (const float*)d_in[0];
  pr.v_in = (const float*)d_in[1];
  pr.e_in = (const float*)d_in[2];
  const int* eidx = (const int*)d_in[3];
  pr.srcs = eidx;
  pr.dsts = eidx + N_EDGES;
  pr.ead = (const float*)d_in[4];
  pr.We1 = (const float*)d_in[7];
  pr.be1 = (const float*)d_in[8];
  pr.We2 = (const float*)d_in[9];
  pr.be2 = (const float*)d_in[10];
  pr.Weo = (const float*)d_in[11];
  pr.beo = (const float*)d_in[12];
  pr.Wv  = (const float*)d_in[13];
  pr.bv  = (const float*)d_in[14];
  pr.Ws1 = (const float*)d_in[15];
  pr.bs1 = (const float*)d_in[16];
  pr.Ws2 = (const float*)d_in[17];
  pr.bs2 = (const float*)d_in[18];

  pr.out_s = (float*)d_out;                            // [N,128]
  pr.out_v = pr.out_s + (size_t)N_NODES * SDIM;        // [N,3]
  pr.out_e = pr.out_v + (size_t)N_NODES * 3;           // [E,128]

  float* ws = (float*)d_ws;
  pr.deginv = ws;                                      // N
  pr.v_acc = pr.deginv + N_NODES;                      // 3N (contiguous after deginv)
  pr.agg = pr.v_acc + (size_t)3 * N_NODES;             // 64N (contiguous)
  pr.Sa = pr.agg + (size_t)64 * N_NODES;               // 64N
  pr.Sb = pr.Sa + (size_t)64 * N_NODES;                // 64N

  void* args[] = { &pr };
  hipLaunchCooperativeKernel((const void*)k_all, dim3(CBLOCKS), dim3(CTHREADS),
                             args, 0, stream);
}

// Round 6
// 2643.707 us; speedup vs baseline: 1.0875x; 1.0875x over previous
//
#include <hip/hip_runtime.h>
#include <hip/hip_cooperative_groups.h>
#include <math.h>

namespace cg = cooperative_groups;

#define N_NODES 40000
#define N_EDGES 512000
#define SDIM 128
#define EDIM 128
#define HID 64
#define DEPTH 4
#define MSG_IN 386   // 2*SDIM + EDIM + 2
#define SCAL_IN 192  // SDIM + HID
#define CUTOFF 5.0f
#define EPS_D 1e-6f

#define TILE_M 16
#define CW 8                     // waves per block
#define CTHREADS 512
#define NTILES (N_EDGES / TILE_M)  // 32000

typedef __attribute__((ext_vector_type(8))) short short8;
typedef __attribute__((ext_vector_type(4))) float f32x4;

struct Params {
  const float *s_in, *v_in, *e_in;
  const int *srcs, *dsts;
  const float *ead;
  const float *We1, *be1, *We2, *be2, *Weo, *beo, *Wv, *bv, *Ws1, *bs1, *Ws2, *bs2;
  float *out_s, *out_v, *out_e;
  float *deginv, *v_acc, *agg, *Sa, *Sb;
};

__device__ __forceinline__ float silu_f(float x) { return x / (1.0f + __expf(-x)); }

__device__ __forceinline__ unsigned short f2b(float x) {
  union { float f; unsigned int u; } v; v.f = x;
  unsigned int r = v.u + 0x7FFFu + ((v.u >> 16) & 1u);
  return (unsigned short)(r >> 16);
}

__device__ __forceinline__ short8 pack8(f32x4 lo, f32x4 hi) {
  union { unsigned short u[8]; short8 s; } pk;
  pk.u[0] = f2b(lo[0]); pk.u[1] = f2b(lo[1]); pk.u[2] = f2b(lo[2]); pk.u[3] = f2b(lo[3]);
  pk.u[4] = f2b(hi[0]); pk.u[5] = f2b(hi[1]); pk.u[6] = f2b(hi[2]); pk.u[7] = f2b(hi[3]);
  return pk.s;
}

// Persistent cooperative kernel; grid sized at runtime from occupancy query.
// Fragment layouts (HW-verified rounds 3/4, absmax 0.031):
//   A[m][k]: m=lane&15, k=(lane>>4)*8+i per 32-wide kc block
//   B[k][n]: n=lane&15, k=(lane>>4)*8+i
//   D[m][n]: n=lane&15, m=(lane>>4)*4+reg
// Resources: LDS 67584 B; launch_bounds(512,2) -> VGPR ~108 (round-3 proven, no spill).
__global__ __launch_bounds__(CTHREADS, 2) void k_all(Params p) {
  cg::grid_group grid = cg::this_grid();

  __shared__ __align__(16) unsigned short W1t[64 * 136];    // [n][k] K=128+8
  __shared__ __align__(16) unsigned short We2t[64 * 72];    // [n][k] K=64+8
  __shared__ __align__(16) unsigned short WeoT[128 * 72];   // [n][k] K=64+8
  __shared__ __align__(16) unsigned short hmS[CW][16 * 72]; // per-wave h/m frag buf
  __shared__ __align__(16) float sbufS[CW][128];            // per-wave scalars / s-row

  const int tid = threadIdx.x;
  const int lane = tid & 63;
  const int w = tid >> 6;
  const int gw = blockIdx.x * CW + w;
  const int nwv = gridDim.x * CW;            // total waves (runtime grid)
  const int nthr = gridDim.x * CTHREADS;     // total threads
  const int c = lane & 15;   // A-row / B-col / D-col
  const int g = lane >> 4;   // k-group / D-row-group

  float* sb = sbufS[w];
  int* sbi = (int*)sb;
  unsigned short* hw = hmS[w];
  float* hf = (float*)hmS[w];

  // ---------------- init: degree ----------------
  {
    const int gt = blockIdx.x * CTHREADS + tid;
    for (int i = gt; i < (1 + 3 + 64) * N_NODES; i += nthr)
      p.deginv[i] = 0.0f;   // deginv, v_acc, agg contiguous
    grid.sync();
    for (int i = gt; i < N_EDGES; i += nthr)
      atomicAdd(&p.deginv[p.dsts[i]], 1.0f);
    grid.sync();
    for (int i = gt; i < N_NODES; i += nthr)
      p.deginv[i] = 1.0f / fmaxf(p.deginv[i], 1.0f);
    grid.sync();
  }

  // ---- stage weights(0) + phase A(0): Sa/Sb from s_in ----
  {
    const float* W1i = p.We1;
    const float* W1e = W1i + 256 * HID;
    for (int idx = tid; idx < 128 * 64; idx += CTHREADS) {
      const int k = idx >> 6, n = idx & 63;
      W1t[n * 136 + k] = f2b(W1e[idx]);
    }
    for (int idx = tid; idx < 64 * 64; idx += CTHREADS) {
      const int k = idx >> 6, n = idx & 63;
      We2t[n * 72 + k] = f2b(p.We2[idx]);
    }
    for (int idx = tid; idx < 64 * 128; idx += CTHREADS) {
      const int k = idx >> 7, n = idx & 127;
      WeoT[n * 72 + k] = f2b(p.Weo[idx]);
    }
    for (int node = gw; node < N_NODES; node += nwv) {
      const float2 s2 = reinterpret_cast<const float2*>(p.s_in + (size_t)node * SDIM)[lane];
      reinterpret_cast<float2*>(sb)[lane] = s2;
      float a = p.be1[lane], b = 0.0f;
#pragma unroll 8
      for (int k = 0; k < SDIM; ++k) {
        const float sk = sb[k];
        a = fmaf(sk, W1i[k * HID + lane], a);
        b = fmaf(sk, W1i[(SDIM + k) * HID + lane], b);
      }
      p.Sa[(size_t)node * HID + lane] = a;
      p.Sb[(size_t)node * HID + lane] = b;
    }
  }
  grid.sync();

  for (int d = 0; d < DEPTH; ++d) {
    const float* scur = d ? p.out_s : p.s_in;
    const float* vcur = d ? p.out_v : p.v_in;
    const float* ecur = d ? p.out_e : p.e_in;
    const float* W1i = p.We1 + (size_t)d * MSG_IN * HID;

    // ---- phase B: edges (wave per 16-edge tile) ----
    {
      const float* w1d = W1i + 384 * HID;
      const float* w1a = W1i + 385 * HID;
      float w1d_l[4], w1a_l[4], be2_l[4], Wv_l[4], beo_l[8];
      const float* be2d = p.be2 + d * HID;
      const float* beod = p.beo + d * EDIM;
      const float* Wvd = p.Wv + d * HID;
#pragma unroll
      for (int nt = 0; nt < 4; ++nt) {
        w1d_l[nt] = w1d[nt * 16 + c];
        w1a_l[nt] = w1a[nt * 16 + c];
        be2_l[nt] = be2d[nt * 16 + c];
        Wv_l[nt] = Wvd[nt * 16 + c];
      }
#pragma unroll
      for (int nt = 0; nt < 8; ++nt) beo_l[nt] = beod[nt * 16 + c];
      const float bv0 = p.bv[d];

      for (int t = gw; t < NTILES; t += nwv) {
        const int e0 = t * TILE_M;
        if (lane < 16) {
          const int eid = e0 + lane;
          const int s_ = p.srcs[eid], d_ = p.dsts[eid];
          const float dx = vcur[s_ * 3 + 0] - vcur[d_ * 3 + 0];
          const float dy = vcur[s_ * 3 + 1] - vcur[d_ * 3 + 1];
          const float dz = vcur[s_ * 3 + 2] - vcur[d_ * 3 + 2];
          const float dist = sqrtf(dx * dx + dy * dy + dz * dz + EPS_D);
          const float cwv = (dist < CUTOFF)
                                ? 0.5f * (__cosf((float)M_PI / CUTOFF * dist) + 1.0f)
                                : 0.0f;
          sb[lane] = dist; sb[16 + lane] = cwv; sb[32 + lane] = p.ead[eid];
          sb[48 + lane] = dx; sb[64 + lane] = dy; sb[80 + lane] = dz;
          sbi[96 + lane] = s_; sbi[112 + lane] = d_;
        }
        int src_r[4], dst_r[4];
        float dist_r[4], cw_r[4], ea_r[4];
#pragma unroll
        for (int r = 0; r < 4; ++r) {
          const int row = g * 4 + r;
          dist_r[r] = sb[row]; cw_r[r] = sb[16 + row]; ea_r[r] = sb[32 + row];
          src_r[r] = sbi[96 + row]; dst_r[r] = sbi[112 + row];
        }

        f32x4 acc[4];
#pragma unroll
        for (int nt = 0; nt < 4; ++nt)
#pragma unroll
          for (int r = 0; r < 4; ++r)
            acc[nt][r] = p.Sa[(size_t)src_r[r] * HID + nt * 16 + c]
                       + p.Sb[(size_t)dst_r[r] * HID + nt * 16 + c]
                       + dist_r[r] * w1d_l[nt] + ea_r[r] * w1a_l[nt];

        // G1: A-frags direct from global (lane c owns row e0+c)
        const float* erow = ecur + (size_t)(e0 + c) * EDIM;
#pragma unroll
        for (int kc = 0; kc < 4; ++kc) {
          const f32x4 lo = *(const f32x4*)&erow[kc * 32 + g * 8];
          const f32x4 hi = *(const f32x4*)&erow[kc * 32 + g * 8 + 4];
          const short8 af = pack8(lo, hi);
#pragma unroll
          for (int nt = 0; nt < 4; ++nt) {
            const short8 bf = *(const short8*)&W1t[(nt * 16 + c) * 136 + kc * 32 + g * 8];
            acc[nt] = __builtin_amdgcn_mfma_f32_16x16x32_bf16(af, bf, acc[nt], 0, 0, 0);
          }
        }
#pragma unroll
        for (int nt = 0; nt < 4; ++nt)
#pragma unroll
          for (int r = 0; r < 4; ++r)
            hw[(g * 4 + r) * 72 + nt * 16 + c] = f2b(silu_f(acc[nt][r]));

        // G2
        f32x4 acc2[4];
#pragma unroll
        for (int nt = 0; nt < 4; ++nt)
          acc2[nt] = f32x4{be2_l[nt], be2_l[nt], be2_l[nt], be2_l[nt]};
#pragma unroll
        for (int kc = 0; kc < 2; ++kc) {
          const short8 am = *(const short8*)&hw[c * 72 + kc * 32 + g * 8];
#pragma unroll
          for (int nt = 0; nt < 4; ++nt) {
            const short8 bf = *(const short8*)&We2t[(nt * 16 + c) * 72 + kc * 32 + g * 8];
            acc2[nt] = __builtin_amdgcn_mfma_f32_16x16x32_bf16(am, bf, acc2[nt], 0, 0, 0);
          }
        }
        float mval[4][4];
#pragma unroll
        for (int nt = 0; nt < 4; ++nt)
#pragma unroll
          for (int r = 0; r < 4; ++r)
            mval[nt][r] = silu_f(acc2[nt][r]) * cw_r[r];

        // agg atomics + wv reduce + v_acc atomics
        float tr[4] = {0.f, 0.f, 0.f, 0.f};
#pragma unroll
        for (int nt = 0; nt < 4; ++nt)
#pragma unroll
          for (int r = 0; r < 4; ++r) {
            tr[r] = fmaf(mval[nt][r], Wv_l[nt], tr[r]);
            atomicAdd(&p.agg[(size_t)dst_r[r] * HID + nt * 16 + c], mval[nt][r]);
          }
#pragma unroll
        for (int r = 0; r < 4; ++r) {
          float s = tr[r];
          s += __shfl_xor(s, 1); s += __shfl_xor(s, 2);
          s += __shfl_xor(s, 4); s += __shfl_xor(s, 8);
          const float wvv = s + bv0;
          if (c < 3) {
            const int row = g * 4 + r;
            atomicAdd(&p.v_acc[(size_t)dst_r[r] * 3 + c], sb[48 + 16 * c + row] * wvv);
          }
        }

        // m -> per-wave LDS (bf16, A-layout)
#pragma unroll
        for (int nt = 0; nt < 4; ++nt)
#pragma unroll
          for (int r = 0; r < 4; ++r)
            hw[(g * 4 + r) * 72 + nt * 16 + c] = f2b(mval[nt][r]);

        // GEMMo
        f32x4 oacc[8];
#pragma unroll
        for (int nt = 0; nt < 8; ++nt) oacc[nt] = f32x4{0.f, 0.f, 0.f, 0.f};
#pragma unroll
        for (int kc = 0; kc < 2; ++kc) {
          const short8 am = *(const short8*)&hw[c * 72 + kc * 32 + g * 8];
#pragma unroll
          for (int nt = 0; nt < 8; ++nt) {
            const short8 bf = *(const short8*)&WeoT[(nt * 16 + c) * 72 + kc * 32 + g * 8];
            oacc[nt] = __builtin_amdgcn_mfma_f32_16x16x32_bf16(am, bf, oacc[nt], 0, 0, 0);
          }
        }
        // residual (L2-hot re-read) + bias + store
#pragma unroll
        for (int nt = 0; nt < 8; ++nt)
#pragma unroll
          for (int r = 0; r < 4; ++r) {
            const size_t gi = (size_t)(e0 + g * 4 + r) * EDIM + nt * 16 + c;
            p.out_e[gi] = oacc[nt][r] + beo_l[nt] + ecur[gi];
          }
      }
    }
    grid.sync();

    // ---- phase C(d) fused with weight-stage(d+1) + A(d+1) ----
    {
      if (d + 1 < DEPTH) {
        const float* W1n = p.We1 + (size_t)(d + 1) * MSG_IN * HID;
        const float* W1en = W1n + 256 * HID;
        const float* We2n = p.We2 + (size_t)(d + 1) * HID * HID;
        const float* Weon = p.Weo + (size_t)(d + 1) * HID * EDIM;
        for (int idx = tid; idx < 128 * 64; idx += CTHREADS) {
          const int k = idx >> 6, n = idx & 63;
          W1t[n * 136 + k] = f2b(W1en[idx]);
        }
        for (int idx = tid; idx < 64 * 64; idx += CTHREADS) {
          const int k = idx >> 6, n = idx & 63;
          We2t[n * 72 + k] = f2b(We2n[idx]);
        }
        for (int idx = tid; idx < 64 * 128; idx += CTHREADS) {
          const int k = idx >> 7, n = idx & 127;
          WeoT[n * 72 + k] = f2b(Weon[idx]);
        }
      }
      const float* bs1d = p.bs1 + d * HID;
      const float* bs2d = p.bs2 + d * SDIM;
      const float* Ws1d = p.Ws1 + (size_t)d * SCAL_IN * HID;
      const float* Ws2d = p.Ws2 + (size_t)d * HID * SDIM;
      const float* W1n = p.We1 + (size_t)(d + 1 < DEPTH ? d + 1 : d) * MSG_IN * HID;
      const float* be1n = p.be1 + (d + 1 < DEPTH ? d + 1 : d) * HID;

      for (int node = gw; node < N_NODES; node += nwv) {
        const float di = p.deginv[node];
        if (lane < 3) {
          p.out_v[(size_t)node * 3 + lane] = vcur[(size_t)node * 3 + lane]
                                           + p.v_acc[(size_t)node * 3 + lane] * di;
          p.v_acc[(size_t)node * 3 + lane] = 0.0f;
        }
        const float2 s2 = reinterpret_cast<const float2*>(scur + (size_t)node * SDIM)[lane];
        reinterpret_cast<float2*>(sb)[lane] = s2;
        const float aj = p.agg[(size_t)node * HID + lane] * di;
        p.agg[(size_t)node * HID + lane] = 0.0f;
        hf[lane] = aj;
        float acc = bs1d[lane];
#pragma unroll 8
        for (int k = 0; k < SDIM; ++k) acc = fmaf(sb[k], Ws1d[k * HID + lane], acc);
#pragma unroll 8
        for (int k = 0; k < HID; ++k) acc = fmaf(hf[k], Ws1d[(SDIM + k) * HID + lane], acc);
        const float h = silu_f(acc);
        hf[lane] = h;
        float o1 = bs2d[lane] + sb[lane];
        float o2 = bs2d[64 + lane] + sb[64 + lane];
#pragma unroll 8
        for (int k = 0; k < HID; ++k) {
          const float hk = hf[k];
          o1 = fmaf(hk, Ws2d[k * SDIM + lane], o1);
          o2 = fmaf(hk, Ws2d[k * SDIM + 64 + lane], o2);
        }
        p.out_s[(size_t)node * SDIM + lane] = o1;
        p.out_s[(size_t)node * SDIM + 64 + lane] = o2;

        if (d + 1 < DEPTH) {
          // A(d+1): reuse the fresh s row (same-wave LDS, lockstep-coherent)
          sb[lane] = o1;
          sb[64 + lane] = o2;
          float a = be1n[lane], b = 0.0f;
#pragma unroll 8
          for (int k = 0; k < SDIM; ++k) {
            const float sk = sb[k];
            a = fmaf(sk, W1n[k * HID + lane], a);
            b = fmaf(sk, W1n[(SDIM + k) * HID + lane], b);
          }
          p.Sa[(size_t)node * HID + lane] = a;
          p.Sb[(size_t)node * HID + lane] = b;
        }
      }
    }
    grid.sync();
  }
}

extern "C" void kernel_launch(void* const* d_in, const int* in_sizes, int n_in,
                              void* d_out, int out_size, void* d_ws, size_t ws_size,
                              hipStream_t stream) {
  Params pr;
  pr.s_in = (const float*)d_in[0];
  pr.v_in = (const float*)d_in[1];
  pr.e_in = (const float*)d_in[2];
  const int* eidx = (const int*)d_in[3];
  pr.srcs = eidx;
  pr.dsts = eidx + N_EDGES;
  pr.ead = (const float*)d_in[4];
  pr.We1 = (const float*)d_in[7];
  pr.be1 = (const float*)d_in[8];
  pr.We2 = (const float*)d_in[9];
  pr.be2 = (const float*)d_in[10];
  pr.Weo = (const float*)d_in[11];
  pr.beo = (const float*)d_in[12];
  pr.Wv  = (const float*)d_in[13];
  pr.bv  = (const float*)d_in[14];
  pr.Ws1 = (const float*)d_in[15];
  pr.bs1 = (const float*)d_in[16];
  pr.Ws2 = (const float*)d_in[17];
  pr.bs2 = (const float*)d_in[18];

  pr.out_s = (float*)d_out;                            // [N,128]
  pr.out_v = pr.out_s + (size_t)N_NODES * SDIM;        // [N,3]
  pr.out_e = pr.out_v + (size_t)N_NODES * 3;           // [E,128]

  float* ws = (float*)d_ws;
  pr.deginv = ws;                                      // N
  pr.v_acc = pr.deginv + N_NODES;                      // 3N (contiguous)
  pr.agg = pr.v_acc + (size_t)3 * N_NODES;             // 64N (contiguous)
  pr.Sa = pr.agg + (size_t)64 * N_NODES;               // 64N
  pr.Sb = pr.Sa + (size_t)64 * N_NODES;                // 64N

  void* args[] = { &pr };

  // Grid sized from the SAME occupancy query the cooperative validator uses.
  int occ = 0;
  if (hipOccupancyMaxActiveBlocksPerMultiprocessor(&occ, k_all, CTHREADS, 0) != hipSuccess
      || occ < 1)
    occ = 1;
  if (occ > 2) occ = 2;          // >2 blocks/CU adds nothing (grid-stride covers work)
  int nblocks = 256 * occ;

  hipError_t err = hipLaunchCooperativeKernel((const void*)k_all, dim3(nblocks),
                                              dim3(CTHREADS), args, 0, stream);
  if (err != hipSuccess && nblocks > 256) {
    nblocks = 256;
    err = hipLaunchCooperativeKernel((const void*)k_all, dim3(nblocks),
                                     dim3(CTHREADS), args, 0, stream);
  }
  if (err != hipSuccess && nblocks > 128) {
    nblocks = 128;
    (void)hipLaunchCooperativeKernel((const void*)k_all, dim3(nblocks),
                                     dim3(CTHREADS), args, 0, stream);
  }
}

// Round 7
// 2227.754 us; speedup vs baseline: 1.2905x; 1.1867x over previous
//
#include <hip/hip_runtime.h>
#include <hip/hip_cooperative_groups.h>
#include <math.h>

namespace cg = cooperative_groups;

#define N_NODES 40000
#define N_EDGES 512000
#define SDIM 128
#define EDIM 128
#define HID 64
#define DEPTH 4
#define MSG_IN 386   // 2*SDIM + EDIM + 2
#define SCAL_IN 192  // SDIM + HID
#define CUTOFF 5.0f
#define EPS_D 1e-6f

#define TILE_M 16
#define NTILES (N_EDGES / TILE_M)  // 32000

typedef __attribute__((ext_vector_type(8))) short short8;
typedef __attribute__((ext_vector_type(4))) float f32x4;

struct Params {
  const float *s_in, *v_in, *e_in;
  const int *srcs, *dsts;
  const float *ead;
  const float *We1, *be1, *We2, *be2, *Weo, *beo, *Wv, *bv, *Ws1, *bs1, *Ws2, *bs2;
  float *out_s, *out_v, *out_e;
  float *deginv, *v_acc, *agg, *Sa, *Sb;
};

__device__ __forceinline__ float silu_f(float x) { return x / (1.0f + __expf(-x)); }

__device__ __forceinline__ unsigned short f2b(float x) {
  union { float f; unsigned int u; } v; v.f = x;
  unsigned int r = v.u + 0x7FFFu + ((v.u >> 16) & 1u);
  return (unsigned short)(r >> 16);
}

__device__ __forceinline__ short8 pack8(f32x4 lo, f32x4 hi) {
  union { unsigned short u[8]; short8 s; } pk;
  pk.u[0] = f2b(lo[0]); pk.u[1] = f2b(lo[1]); pk.u[2] = f2b(lo[2]); pk.u[3] = f2b(lo[3]);
  pk.u[4] = f2b(hi[0]); pk.u[5] = f2b(hi[1]); pk.u[6] = f2b(hi[2]); pk.u[7] = f2b(hi[3]);
  return pk.s;
}

// Persistent cooperative kernel, round-3 memory patterns restored.
// Fragment layouts (HW-verified rounds 3/4/6, absmax 0.031):
//   A[m][k]: m=lane&15, k=(lane>>4)*8+i per 32-wide kc block
//   B[k][n]: n=lane&15, k=(lane>>4)*8+i
//   D[m][n]: n=lane&15, m=(lane>>4)*4+reg
// CW=16: LDS = 45056 + 16*(4352+2304+512) = 159744 B (fits 160 KiB), 1 block/CU,
//        16 waves/CU. launch_bounds(1024,1) -> 128 VGPR cap (2nd arg = blocks/CU
//        on this toolchain: r4 (1024,4)->64 VGPR, r6 (512,2)->124 VGPR).
template <int CW>
__global__ __launch_bounds__(CW * 64, 16 / CW) void k_all(Params p) {
  cg::grid_group grid = cg::this_grid();
  constexpr int NT = CW * 64;

  __shared__ __align__(16) unsigned short W1t[64 * 136];     // [n][k] K=128+8
  __shared__ __align__(16) unsigned short We2t[64 * 72];     // [n][k] K=64+8
  __shared__ __align__(16) unsigned short WeoT[128 * 72];    // [n][k] K=64+8
  __shared__ __align__(16) unsigned short eTS[CW][16 * 136]; // per-wave e tile / f32 epilogue scratch
  __shared__ __align__(16) unsigned short hmS[CW][16 * 72];  // per-wave h/m frag buf
  __shared__ __align__(16) float sbufS[CW][128];             // per-wave scalars / s-row

  const int tid = threadIdx.x;
  const int lane = tid & 63;
  const int w = tid >> 6;
  const int gw = blockIdx.x * CW + w;
  const int nwv = gridDim.x * CW;
  const int nthr = gridDim.x * NT;
  const int c = lane & 15;   // A-row / B-col / D-col
  const int g = lane >> 4;   // k-group / D-row-group

  float* sb = sbufS[w];
  int* sbi = (int*)sb;
  unsigned short* hw = hmS[w];
  unsigned short* eTw = eTS[w];
  float* ef = (float*)eTS[w];   // epilogue bounce (16*68 floats = 4352 B, fits)
  float* hf = (float*)hmS[w];   // node-phase 64-float buf

  // ---------------- init: degree ----------------
  {
    const int gt = blockIdx.x * NT + tid;
    for (int i = gt; i < (1 + 3 + 64) * N_NODES; i += nthr)
      p.deginv[i] = 0.0f;   // deginv, v_acc, agg contiguous
    grid.sync();
    for (int i = gt; i < N_EDGES; i += nthr)
      atomicAdd(&p.deginv[p.dsts[i]], 1.0f);
    grid.sync();
    for (int i = gt; i < N_NODES; i += nthr)
      p.deginv[i] = 1.0f / fmaxf(p.deginv[i], 1.0f);
    grid.sync();
  }

  // ---- stage weights(0) + phase A(0): Sa/Sb from s_in ----
  {
    const float* W1i = p.We1;
    const float* W1e = W1i + 256 * HID;
    for (int idx = tid; idx < 128 * 64; idx += NT) {
      const int k = idx >> 6, n = idx & 63;
      W1t[n * 136 + k] = f2b(W1e[idx]);
    }
    for (int idx = tid; idx < 64 * 64; idx += NT) {
      const int k = idx >> 6, n = idx & 63;
      We2t[n * 72 + k] = f2b(p.We2[idx]);
    }
    for (int idx = tid; idx < 64 * 128; idx += NT) {
      const int k = idx >> 7, n = idx & 127;
      WeoT[n * 72 + k] = f2b(p.Weo[idx]);
    }
    for (int node = gw; node < N_NODES; node += nwv) {
      const float2 s2 = reinterpret_cast<const float2*>(p.s_in + (size_t)node * SDIM)[lane];
      reinterpret_cast<float2*>(sb)[lane] = s2;
      float a = p.be1[lane], b = 0.0f;
#pragma unroll 8
      for (int k = 0; k < SDIM; ++k) {
        const float sk = sb[k];
        a = fmaf(sk, W1i[k * HID + lane], a);
        b = fmaf(sk, W1i[(SDIM + k) * HID + lane], b);
      }
      p.Sa[(size_t)node * HID + lane] = a;
      p.Sb[(size_t)node * HID + lane] = b;
    }
  }
  grid.sync();

  for (int d = 0; d < DEPTH; ++d) {
    const float* scur = d ? p.out_s : p.s_in;
    const float* vcur = d ? p.out_v : p.v_in;
    const float* ecur = d ? p.out_e : p.e_in;
    const float* W1i = p.We1 + (size_t)d * MSG_IN * HID;

    // ---- phase B: edges (wave per 16-edge tile) ----
    {
      const float* w1d = W1i + 384 * HID;
      const float* w1a = W1i + 385 * HID;
      float w1d_l[4], w1a_l[4], be2_l[4], Wv_l[4];
      const float* be2d = p.be2 + d * HID;
      const float* beod = p.beo + d * EDIM;
      const float* Wvd = p.Wv + d * HID;
#pragma unroll
      for (int nt = 0; nt < 4; ++nt) {
        w1d_l[nt] = w1d[nt * 16 + c];
        w1a_l[nt] = w1a[nt * 16 + c];
        be2_l[nt] = be2d[nt * 16 + c];
        Wv_l[nt] = Wvd[nt * 16 + c];
      }
      f32x4 beoV[2];
      beoV[0] = *(const f32x4*)&beod[c * 4];
      beoV[1] = *(const f32x4*)&beod[64 + c * 4];
      const float bv0 = p.bv[d];

      for (int t = gw; t < NTILES; t += nwv) {
        const int e0 = t * TILE_M;
        if (lane < 16) {
          const int eid = e0 + lane;
          const int s_ = p.srcs[eid], d_ = p.dsts[eid];
          const float dx = vcur[s_ * 3 + 0] - vcur[d_ * 3 + 0];
          const float dy = vcur[s_ * 3 + 1] - vcur[d_ * 3 + 1];
          const float dz = vcur[s_ * 3 + 2] - vcur[d_ * 3 + 2];
          const float dist = sqrtf(dx * dx + dy * dy + dz * dz + EPS_D);
          const float cwv = (dist < CUTOFF)
                                ? 0.5f * (__cosf((float)M_PI / CUTOFF * dist) + 1.0f)
                                : 0.0f;
          sb[lane] = dist; sb[16 + lane] = cwv; sb[32 + lane] = p.ead[eid];
          sb[48 + lane] = dx; sb[64 + lane] = dy; sb[80 + lane] = dz;
          sbi[96 + lane] = s_; sbi[112 + lane] = d_;
        }

        // ---- stage e tile: coalesced f32x4 loads -> bf16 LDS (A-layout) ----
        {
          const f32x4* ebase = (const f32x4*)(ecur + (size_t)e0 * EDIM);
#pragma unroll
          for (int i = 0; i < 4; ++i) {
            const int f = i * 128 + lane * 2;  // f32x4 units, 32/row
            const f32x4 a = ebase[f];
            const f32x4 b = ebase[f + 1];
            const int row = i * 4 + g;
            *(short8*)&eTw[row * 136 + c * 8] = pack8(a, b);
          }
        }

        int src_r[4], dst_r[4];
        float dist_r[4], cw_r[4], ea_r[4];
#pragma unroll
        for (int r = 0; r < 4; ++r) {
          const int row = g * 4 + r;
          dist_r[r] = sb[row]; cw_r[r] = sb[16 + row]; ea_r[r] = sb[32 + row];
          src_r[r] = sbi[96 + row]; dst_r[r] = sbi[112 + row];
        }

        f32x4 acc[4];
#pragma unroll
        for (int nt = 0; nt < 4; ++nt)
#pragma unroll
          for (int r = 0; r < 4; ++r)
            acc[nt][r] = p.Sa[(size_t)src_r[r] * HID + nt * 16 + c]
                       + p.Sb[(size_t)dst_r[r] * HID + nt * 16 + c]
                       + dist_r[r] * w1d_l[nt] + ea_r[r] * w1a_l[nt];

        // G1: e @ W1e (K=128)
#pragma unroll
        for (int kc = 0; kc < 4; ++kc) {
          const short8 af = *(const short8*)&eTw[c * 136 + kc * 32 + g * 8];
#pragma unroll
          for (int nt = 0; nt < 4; ++nt) {
            const short8 bf = *(const short8*)&W1t[(nt * 16 + c) * 136 + kc * 32 + g * 8];
            acc[nt] = __builtin_amdgcn_mfma_f32_16x16x32_bf16(af, bf, acc[nt], 0, 0, 0);
          }
        }
#pragma unroll
        for (int nt = 0; nt < 4; ++nt)
#pragma unroll
          for (int r = 0; r < 4; ++r)
            hw[(g * 4 + r) * 72 + nt * 16 + c] = f2b(silu_f(acc[nt][r]));

        // G2: h1 @ We2 (K=64)
        f32x4 acc2[4];
#pragma unroll
        for (int nt = 0; nt < 4; ++nt)
          acc2[nt] = f32x4{be2_l[nt], be2_l[nt], be2_l[nt], be2_l[nt]};
#pragma unroll
        for (int kc = 0; kc < 2; ++kc) {
          const short8 am = *(const short8*)&hw[c * 72 + kc * 32 + g * 8];
#pragma unroll
          for (int nt = 0; nt < 4; ++nt) {
            const short8 bf = *(const short8*)&We2t[(nt * 16 + c) * 72 + kc * 32 + g * 8];
            acc2[nt] = __builtin_amdgcn_mfma_f32_16x16x32_bf16(am, bf, acc2[nt], 0, 0, 0);
          }
        }
        float mval[4][4];
#pragma unroll
        for (int nt = 0; nt < 4; ++nt)
#pragma unroll
          for (int r = 0; r < 4; ++r)
            mval[nt][r] = silu_f(acc2[nt][r]) * cw_r[r];

        // agg atomics + wv reduce + v_acc atomics
        float tr[4] = {0.f, 0.f, 0.f, 0.f};
#pragma unroll
        for (int nt = 0; nt < 4; ++nt)
#pragma unroll
          for (int r = 0; r < 4; ++r) {
            tr[r] = fmaf(mval[nt][r], Wv_l[nt], tr[r]);
            atomicAdd(&p.agg[(size_t)dst_r[r] * HID + nt * 16 + c], mval[nt][r]);
          }
#pragma unroll
        for (int r = 0; r < 4; ++r) {
          float s = tr[r];
          s += __shfl_xor(s, 1); s += __shfl_xor(s, 2);
          s += __shfl_xor(s, 4); s += __shfl_xor(s, 8);
          const float wvv = s + bv0;
          if (c < 3) {
            const int row = g * 4 + r;
            atomicAdd(&p.v_acc[(size_t)dst_r[r] * 3 + c], sb[48 + 16 * c + row] * wvv);
          }
        }

        // m -> per-wave LDS (bf16, A-layout)
#pragma unroll
        for (int nt = 0; nt < 4; ++nt)
#pragma unroll
          for (int r = 0; r < 4; ++r)
            hw[(g * 4 + r) * 72 + nt * 16 + c] = f2b(mval[nt][r]);

        // GEMMo: m @ Weo (K=64, 128 cols)
        f32x4 oacc[8];
#pragma unroll
        for (int nt = 0; nt < 8; ++nt) oacc[nt] = f32x4{0.f, 0.f, 0.f, 0.f};
#pragma unroll
        for (int kc = 0; kc < 2; ++kc) {
          const short8 am = *(const short8*)&hw[c * 72 + kc * 32 + g * 8];
#pragma unroll
          for (int nt = 0; nt < 8; ++nt) {
            const short8 bf = *(const short8*)&WeoT[(nt * 16 + c) * 72 + kc * 32 + g * 8];
            oacc[nt] = __builtin_amdgcn_mfma_f32_16x16x32_bf16(am, bf, oacc[nt], 0, 0, 0);
          }
        }

        // epilogue: bounce each 64-col half through f32 LDS (eTw scratch, free
        // after G1), then coalesced f32x4 residual load + store (256B segments)
#pragma unroll
        for (int h2 = 0; h2 < 2; ++h2) {
#pragma unroll
          for (int nt = 0; nt < 4; ++nt)
#pragma unroll
            for (int r = 0; r < 4; ++r)
              ef[(g * 4 + r) * 68 + nt * 16 + c] = oacc[h2 * 4 + nt][r];
#pragma unroll
          for (int q = 0; q < 4; ++q) {
            const int row = q * 4 + g;
            const f32x4 val = *(const f32x4*)&ef[row * 68 + c * 4];
            const size_t gi = (size_t)(e0 + row) * EDIM + h2 * 64 + c * 4;
            const f32x4 old = *(const f32x4*)&ecur[gi];
            *(f32x4*)&p.out_e[gi] = val + beoV[h2] + old;
          }
        }
      }
    }
    grid.sync();

    // ---- phase C(d) fused with weight-stage(d+1) + A(d+1) ----
    {
      if (d + 1 < DEPTH) {
        const float* W1n = p.We1 + (size_t)(d + 1) * MSG_IN * HID;
        const float* W1en = W1n + 256 * HID;
        const float* We2n = p.We2 + (size_t)(d + 1) * HID * HID;
        const float* Weon = p.Weo + (size_t)(d + 1) * HID * EDIM;
        for (int idx = tid; idx < 128 * 64; idx += NT) {
          const int k = idx >> 6, n = idx & 63;
          W1t[n * 136 + k] = f2b(W1en[idx]);
        }
        for (int idx = tid; idx < 64 * 64; idx += NT) {
          const int k = idx >> 6, n = idx & 63;
          We2t[n * 72 + k] = f2b(We2n[idx]);
        }
        for (int idx = tid; idx < 64 * 128; idx += NT) {
          const int k = idx >> 7, n = idx & 127;
          WeoT[n * 72 + k] = f2b(Weon[idx]);
        }
      }
      const float* bs1d = p.bs1 + d * HID;
      const float* bs2d = p.bs2 + d * SDIM;
      const float* Ws1d = p.Ws1 + (size_t)d * SCAL_IN * HID;
      const float* Ws2d = p.Ws2 + (size_t)d * HID * SDIM;
      const int dn = (d + 1 < DEPTH) ? d + 1 : d;
      const float* W1n = p.We1 + (size_t)dn * MSG_IN * HID;
      const float* be1n = p.be1 + dn * HID;

      for (int node = gw; node < N_NODES; node += nwv) {
        const float di = p.deginv[node];
        if (lane < 3) {
          p.out_v[(size_t)node * 3 + lane] = vcur[(size_t)node * 3 + lane]
                                           + p.v_acc[(size_t)node * 3 + lane] * di;
          p.v_acc[(size_t)node * 3 + lane] = 0.0f;
        }
        const float2 s2 = reinterpret_cast<const float2*>(scur + (size_t)node * SDIM)[lane];
        reinterpret_cast<float2*>(sb)[lane] = s2;
        const float aj = p.agg[(size_t)node * HID + lane] * di;
        p.agg[(size_t)node * HID + lane] = 0.0f;
        hf[lane] = aj;
        float acc = bs1d[lane];
#pragma unroll 8
        for (int k = 0; k < SDIM; ++k) acc = fmaf(sb[k], Ws1d[k * HID + lane], acc);
#pragma unroll 8
        for (int k = 0; k < HID; ++k) acc = fmaf(hf[k], Ws1d[(SDIM + k) * HID + lane], acc);
        const float h = silu_f(acc);
        hf[lane] = h;
        float o1 = bs2d[lane] + sb[lane];
        float o2 = bs2d[64 + lane] + sb[64 + lane];
#pragma unroll 8
        for (int k = 0; k < HID; ++k) {
          const float hk = hf[k];
          o1 = fmaf(hk, Ws2d[k * SDIM + lane], o1);
          o2 = fmaf(hk, Ws2d[k * SDIM + 64 + lane], o2);
        }
        p.out_s[(size_t)node * SDIM + lane] = o1;
        p.out_s[(size_t)node * SDIM + 64 + lane] = o2;

        if (d + 1 < DEPTH) {
          // A(d+1): reuse fresh s row (same-wave LDS, lockstep-coherent)
          sb[lane] = o1;
          sb[64 + lane] = o2;
          float a = be1n[lane], b = 0.0f;
#pragma unroll 8
          for (int k = 0; k < SDIM; ++k) {
            const float sk = sb[k];
            a = fmaf(sk, W1n[k * HID + lane], a);
            b = fmaf(sk, W1n[(SDIM + k) * HID + lane], b);
          }
          p.Sa[(size_t)node * HID + lane] = a;
          p.Sb[(size_t)node * HID + lane] = b;
        }
      }
    }
    grid.sync();
  }
}

extern "C" void kernel_launch(void* const* d_in, const int* in_sizes, int n_in,
                              void* d_out, int out_size, void* d_ws, size_t ws_size,
                              hipStream_t stream) {
  Params pr;
  pr.s_in = (const float*)d_in[0];
  pr.v_in = (const float*)d_in[1];
  pr.e_in = (const float*)d_in[2];
  const int* eidx = (const int*)d_in[3];
  pr.srcs = eidx;
  pr.dsts = eidx + N_EDGES;
  pr.ead = (const float*)d_in[4];
  pr.We1 = (const float*)d_in[7];
  pr.be1 = (const float*)d_in[8];
  pr.We2 = (const float*)d_in[9];
  pr.be2 = (const float*)d_in[10];
  pr.Weo = (const float*)d_in[11];
  pr.beo = (const float*)d_in[12];
  pr.Wv  = (const float*)d_in[13];
  pr.bv  = (const float*)d_in[14];
  pr.Ws1 = (const float*)d_in[15];
  pr.bs1 = (const float*)d_in[16];
  pr.Ws2 = (const float*)d_in[17];
  pr.bs2 = (const float*)d_in[18];

  pr.out_s = (float*)d_out;                            // [N,128]
  pr.out_v = pr.out_s + (size_t)N_NODES * SDIM;        // [N,3]
  pr.out_e = pr.out_v + (size_t)N_NODES * 3;           // [E,128]

  float* ws = (float*)d_ws;
  pr.deginv = ws;                                      // N
  pr.v_acc = pr.deginv + N_NODES;                      // 3N (contiguous)
  pr.agg = pr.v_acc + (size_t)3 * N_NODES;             // 64N (contiguous)
  pr.Sa = pr.agg + (size_t)64 * N_NODES;               // 64N
  pr.Sb = pr.Sa + (size_t)64 * N_NODES;                // 64N

  void* args[] = { &pr };

  // Prefer CW=16 (1 x 1024-thr block/CU, 156 KiB LDS). Probe launchability via
  // occupancy query FIRST (a failed launch could invalidate graph capture).
  int occ16 = 0;
  hipError_t qerr =
      hipOccupancyMaxActiveBlocksPerMultiprocessor(&occ16, k_all<16>, 1024, 0);
  if (qerr == hipSuccess && occ16 >= 1) {
    if (hipLaunchCooperativeKernel((const void*)k_all<16>, dim3(256), dim3(1024),
                                   args, 0, stream) == hipSuccess)
      return;
  }
  if (hipLaunchCooperativeKernel((const void*)k_all<8>, dim3(256), dim3(512),
                                 args, 0, stream) != hipSuccess) {
    (void)hipLaunchCooperativeKernel((const void*)k_all<8>, dim3(128), dim3(512),
                                     args, 0, stream);
  }
}